// Round 4
// baseline (268.579 us; speedup 1.0000x reference)
//
#include <hip/hip_runtime.h>
#include <hip/hip_cooperative_groups.h>

namespace cg = cooperative_groups;

// Batched gather-GEMV:
//   out[bp, d] = (sum_h hs[bp, h] * W[props[bp], h, d] + bias[props[bp], d]) * mask[bp]
// B*P = 65536, H = 512, D = 2, NPROP = 10000.
//
// v5: single persistent cooperative kernel.
// v4 used 3 serialized dispatches (memset, bucket, per-prop gemv): two full
// device drain/ramp boundaries + a memset dispatch ~= 8-10 us of overhead on
// a ~26 us mandatory-traffic job. v5 fuses all phases with grid.sync():
//   phase 0: zero counts        (trivial)
//   phase 1: atomic bucket scatter by property
//   phase 2: per-prop GEMV, W cached in 16 VGPRs, 4 waves split each bucket,
//            paired 2-entry reduction (7 shfls / pair), grid-strided props
//            (concurrent blocks touch adjacent props -> adjacent W rows).
//   phase 3: overflow sweep (normally empty).

#define H 512
#define D 2
#define CAP 48           // slots per property; Poisson(6.55) => P(count>48) ~ 0
#define KSPLIT 4         // waves per property
#define COOP_BLOCKS 1536 // 6 blocks/CU x 256 CUs (matches __launch_bounds__(256,6))
#define OVF_BLOCKS 64    // fallback-path cleanup blocks

// ---------------------------------------------------------------------------
// Shared per-bp GEMV body (verified layout), for overflow/fallback paths:
//   lane i, chunk k: W4[prop*256 + 64k + i] packs (W[h,0],W[h,1],W[h+1,0],W[h+1,1])
//                    hs2[bp*256  + 64k + i] packs (hs[h], hs[h+1]),  h = 128k + 2i
// ---------------------------------------------------------------------------
__device__ __forceinline__ void gemv_one_bp(
    const float* __restrict__ hs, const float* __restrict__ mask,
    const float* __restrict__ W,  const float* __restrict__ bias,
    float* __restrict__ out, int bp, int prop, int lane)
{
    const float2* h2 = (const float2*)(hs + (size_t)bp * H);
    const float4* w4 = (const float4*)(W + (size_t)prop * (H * D));

    float2 ha = h2[lane];
    float2 hb = h2[64 + lane];
    float2 hc = h2[128 + lane];
    float2 hd = h2[192 + lane];
    float4 wa = w4[lane];
    float4 wb = w4[64 + lane];
    float4 wc = w4[128 + lane];
    float4 wd = w4[192 + lane];

    float s0 = ha.x * wa.x + ha.y * wa.z
             + hb.x * wb.x + hb.y * wb.z
             + hc.x * wc.x + hc.y * wc.z
             + hd.x * wd.x + hd.y * wd.z;
    float s1 = ha.x * wa.y + ha.y * wa.w
             + hb.x * wb.y + hb.y * wb.w
             + hc.x * wc.y + hc.y * wc.w
             + hd.x * wd.y + hd.y * wd.w;

    #pragma unroll
    for (int off = 32; off > 0; off >>= 1) {
        s0 += __shfl_xor(s0, off, 64);
        s1 += __shfl_xor(s1, off, 64);
    }

    if (lane == 0) {
        const float m  = mask[bp];
        const float b0 = bias[(size_t)prop * D + 0];
        const float b1 = bias[(size_t)prop * D + 1];
        float2 r;
        r.x = (s0 + b0) * m;
        r.y = (s1 + b1) * m;
        *(float2*)(out + (size_t)bp * D) = r;
    }
}

// ---------------------------------------------------------------------------
// GEMV body for one prop's bucket slice owned by this wave (paired reduction).
// ---------------------------------------------------------------------------
__device__ __forceinline__ void gemv_prop_wave(
    const float* __restrict__ hs, const float* __restrict__ mask,
    const float* __restrict__ W,  const float* __restrict__ bias,
    float* __restrict__ out, const int* __restrict__ slots,
    int p, int cnt, int k, int lane)
{
    const int nt = (cnt - k + KSPLIT - 1) / KSPLIT;   // my entry count (<=12)
    if (nt <= 0) return;

    // W for this property, resident in 16 VGPRs.
    const float4* w4 = (const float4*)(W + (size_t)p * (H * D));
    const float4 wa = w4[lane];
    const float4 wb = w4[64 + lane];
    const float4 wc = w4[128 + lane];
    const float4 wd = w4[192 + lane];
    const float b0 = bias[(size_t)p * D + 0];
    const float b1 = bias[(size_t)p * D + 1];
    const float bsel = (lane & 1) ? b1 : b0;

    // lane t holds the slot for my t-th entry (k + KSPLIT*t).
    const int myslot = (lane < nt) ? slots[p * CAP + k + KSPLIT * lane] : 0;

    for (int u = 0; u < nt; u += 2) {
        const int  bpA  = __shfl(myslot, u, 64);
        const bool hasB = (u + 1 < nt);
        const int  bpB  = __shfl(myslot, hasB ? (u + 1) : u, 64);

        const float2* hA = (const float2*)(hs + (size_t)bpA * H);
        float2 a0 = hA[lane];
        float2 a1 = hA[64 + lane];
        float2 a2 = hA[128 + lane];
        float2 a3 = hA[192 + lane];
        float2 c0, c1, c2, c3;
        if (hasB) {
            const float2* hB = (const float2*)(hs + (size_t)bpB * H);
            c0 = hB[lane];
            c1 = hB[64 + lane];
            c2 = hB[128 + lane];
            c3 = hB[192 + lane];
        } else {
            c0 = c1 = c2 = c3 = make_float2(0.f, 0.f);
        }

        float s0A = a0.x * wa.x + a0.y * wa.z
                  + a1.x * wb.x + a1.y * wb.z
                  + a2.x * wc.x + a2.y * wc.z
                  + a3.x * wd.x + a3.y * wd.z;
        float s1A = a0.x * wa.y + a0.y * wa.w
                  + a1.x * wb.y + a1.y * wb.w
                  + a2.x * wc.y + a2.y * wc.w
                  + a3.x * wd.y + a3.y * wd.w;
        float s0B = c0.x * wa.x + c0.y * wa.z
                  + c1.x * wb.x + c1.y * wb.z
                  + c2.x * wc.x + c2.y * wc.z
                  + c3.x * wd.x + c3.y * wd.z;
        float s1B = c0.x * wa.y + c0.y * wa.w
                  + c1.x * wb.y + c1.y * wb.w
                  + c2.x * wc.y + c2.y * wc.w
                  + c3.x * wd.y + c3.y * wd.w;

        // Joint reduction: 7 shfls for all four dot products.
        const bool o1 = (lane & 1) != 0;
        float keepA = o1 ? s1A : s0A;
        float sendA = o1 ? s0A : s1A;
        float vA = keepA + __shfl_xor(sendA, 1, 64);
        float keepB = o1 ? s1B : s0B;
        float sendB = o1 ? s0B : s1B;
        float vB = keepB + __shfl_xor(sendB, 1, 64);
        const bool o2 = (lane & 2) != 0;
        float keep = o2 ? vB : vA;
        float send = o2 ? vA : vB;
        float w = keep + __shfl_xor(send, 2, 64);
        #pragma unroll
        for (int off = 4; off <= 32; off <<= 1)
            w += __shfl_xor(w, off, 64);

        // lane 0: s0A, lane 1: s1A, lane 2: s0B, lane 3: s1B.
        if (lane < (hasB ? 4 : 2)) {
            const int bps = (lane & 2) ? bpB : bpA;
            const float m = mask[bps];
            out[(size_t)bps * D + (lane & 1)] = (w + bsel) * m;
        }
    }
}

// ---------------------------------------------------------------------------
// v5: single persistent cooperative kernel (all phases).
// ---------------------------------------------------------------------------
__global__ __launch_bounds__(256, 6) void fused_kernel(
    const float* __restrict__ hs,
    const int*   __restrict__ props,
    const float* __restrict__ mask,
    const float* __restrict__ W,
    const float* __restrict__ bias,
    float*       __restrict__ out,
    int*         __restrict__ counts,   // [nprop+1] (last = ovf_cnt)
    int*         __restrict__ slots,    // [nprop * CAP]
    int*         __restrict__ ovf,      // [BP]
    int nprop, int BP)
{
    cg::grid_group grid = cg::this_grid();
    const int tid      = blockIdx.x * blockDim.x + threadIdx.x;
    const int nthreads = gridDim.x * blockDim.x;
    int* ovf_cnt = counts + nprop;

    // --- phase 0: zero counts (+ ovf_cnt) ---
    for (int i = tid; i < nprop + 1; i += nthreads) counts[i] = 0;
    grid.sync();

    // --- phase 1: bucket bp-pairs by property ---
    for (int i = tid; i < BP; i += nthreads) {
        const int p = props[i];
        const int idx = atomicAdd(&counts[p], 1);
        if (idx < CAP) {
            slots[p * CAP + idx] = i;
        } else {
            const int o = atomicAdd(ovf_cnt, 1);
            ovf[o] = i;
        }
    }
    grid.sync();

    // --- phase 2: per-prop GEMV, grid-strided props, 4-wave bucket split ---
    const int k    = threadIdx.x >> 6;   // sub-wave 0..3
    const int lane = threadIdx.x & 63;
    for (int p = blockIdx.x; p < nprop; p += gridDim.x) {
        int cnt = counts[p];
        if (cnt > CAP) cnt = CAP;
        if (cnt == 0) continue;
        gemv_prop_wave(hs, mask, W, bias, out, slots, p, cnt, k, lane);
    }

    // --- phase 3: overflow sweep (normally empty) ---
    const int nov = *ovf_cnt;
    if (nov > 0) {
        const int gwid = tid >> 6;
        const int totw = nthreads >> 6;
        for (int i = gwid; i < nov; i += totw) {
            const int bp = ovf[i];
            gemv_one_bp(hs, mask, W, bias, out, bp, props[bp], lane);
        }
    }
}

// ---------------------------------------------------------------------------
// Fallback path A: 3-dispatch version (if cooperative launch unavailable).
// ---------------------------------------------------------------------------
__global__ __launch_bounds__(256) void bucket_kernel(
    const int* __restrict__ props, int BP,
    int* __restrict__ counts, int* __restrict__ slots,
    int* __restrict__ ovf_cnt, int* __restrict__ ovf)
{
    int i = blockIdx.x * blockDim.x + threadIdx.x;
    const int stride = gridDim.x * blockDim.x;
    for (; i < BP; i += stride) {
        const int p = props[i];
        const int idx = atomicAdd(&counts[p], 1);
        if (idx < CAP) {
            slots[p * CAP + idx] = i;
        } else {
            const int o = atomicAdd(ovf_cnt, 1);
            ovf[o] = i;
        }
    }
}

__global__ __launch_bounds__(256) void per_prop_kernel(
    const float* __restrict__ hs,
    const int*   __restrict__ props,
    const float* __restrict__ mask,
    const float* __restrict__ W,
    const float* __restrict__ bias,
    float*       __restrict__ out,
    const int*   __restrict__ counts,
    const int*   __restrict__ slots,
    const int*   __restrict__ ovf_cnt,
    const int*   __restrict__ ovf,
    int nprop)
{
    const int k    = threadIdx.x >> 6;
    const int lane = threadIdx.x & 63;

    if (blockIdx.x < nprop) {
        const int p = blockIdx.x;
        int cnt = counts[p];
        if (cnt > CAP) cnt = CAP;
        if (cnt == 0) return;
        gemv_prop_wave(hs, mask, W, bias, out, slots, p, cnt, k, lane);
    } else {
        const int wv = (blockIdx.x - nprop) * KSPLIT + k;
        const int n = *ovf_cnt;
        for (int i = wv; i < n; i += OVF_BLOCKS * KSPLIT) {
            const int bp = ovf[i];
            gemv_one_bp(hs, mask, W, bias, out, bp, props[bp], lane);
        }
    }
}

// ---------------------------------------------------------------------------
// Fallback path B: original per-bp kernel (workspace too small).
// ---------------------------------------------------------------------------
__global__ __launch_bounds__(256) void adapter_gemv_kernel(
    const float* __restrict__ hs,
    const int*   __restrict__ props,
    const float* __restrict__ mask,
    const float* __restrict__ W,
    const float* __restrict__ bias,
    float* __restrict__ out,
    int BP)
{
    const int tid  = blockIdx.x * blockDim.x + threadIdx.x;
    const int bp   = tid >> 6;
    const int lane = tid & 63;
    if (bp >= BP) return;
    gemv_one_bp(hs, mask, W, bias, out, bp, props[bp], lane);
}

extern "C" void kernel_launch(void* const* d_in, const int* in_sizes, int n_in,
                              void* d_out, int out_size, void* d_ws, size_t ws_size,
                              hipStream_t stream) {
    const float* hs    = (const float*)d_in[0];
    const int*   props = (const int*)d_in[1];
    const float* mask  = (const float*)d_in[2];
    const float* W     = (const float*)d_in[3];
    const float* bias  = (const float*)d_in[4];
    float* out = (float*)d_out;

    int BP    = in_sizes[1];                 // 512 * 128 = 65536 pairs
    int nprop = in_sizes[3] / (H * D);       // 10000

    // Workspace layout (all int32):
    //   [0, nprop+1)              : counts + ovf_cnt
    //   slots at 256B-aligned off : nprop * CAP
    //   ovf   after slots         : BP
    const size_t off_counts = 0;
    const size_t off_slots  = (((size_t)(nprop + 1) * 4) + 255) & ~(size_t)255;
    const size_t off_ovf    = off_slots + (size_t)nprop * CAP * 4;
    const size_t ws_needed  = off_ovf + (size_t)BP * 4;

    if (ws_size < ws_needed) {
        // Not enough workspace: original verified path.
        const int threads = 256;
        const int blocks  = (BP * 64 + threads - 1) / threads;
        adapter_gemv_kernel<<<blocks, threads, 0, stream>>>(hs, props, mask, W, bias, out, BP);
        return;
    }

    int* counts  = (int*)((char*)d_ws + off_counts);
    int* ovf_cnt = counts + nprop;
    int* slots   = (int*)((char*)d_ws + off_slots);
    int* ovf     = (int*)((char*)d_ws + off_ovf);

    // --- primary: single cooperative dispatch ---
    {
        void* args[] = {
            (void*)&hs, (void*)&props, (void*)&mask, (void*)&W, (void*)&bias,
            (void*)&out, (void*)&counts, (void*)&slots, (void*)&ovf,
            (void*)&nprop, (void*)&BP
        };
        hipError_t err = hipLaunchCooperativeKernel(
            (const void*)fused_kernel, dim3(COOP_BLOCKS), dim3(256),
            args, 0, stream);
        if (err == hipSuccess) return;
        // else: fall through to the 3-dispatch path
        (void)hipGetLastError();   // clear error state
    }

    // --- fallback: memset + bucket + per-prop ---
    hipMemsetAsync(counts, 0, (size_t)(nprop + 1) * 4, stream);
    {
        const int threads = 256;
        int blocks = (BP + threads - 1) / threads;
        if (blocks > 1024) blocks = 1024;
        bucket_kernel<<<blocks, threads, 0, stream>>>(props, BP, counts, slots, ovf_cnt, ovf);
    }
    {
        const int threads = 256;
        const int blocks  = nprop + OVF_BLOCKS;
        per_prop_kernel<<<blocks, threads, 0, stream>>>(
            hs, props, mask, W, bias, out, counts, slots, ovf_cnt, ovf, nprop);
    }
}

// Round 5
// 59.187 us; speedup vs baseline: 4.5378x; 4.5378x over previous
//
#include <hip/hip_runtime.h>

// Batched gather-GEMV:
//   out[bp, d] = (sum_h hs[bp, h] * W[props[bp], h, d] + bias[props[bp], d]) * mask[bp]
// B*P = 65536, H = 512, D = 2, NPROP = 10000.
//
// v6: two stream-ordered dispatches (NO cooperative launch: v5 showed
// grid.sync() costs ~250 us on gfx950).
//   1) bucket_zero_kernel: 128 blocks, each OWNS a prop range; zeroes its
//      counters in LDS, scans the whole props array (redundant reads are
//      L2-served), buckets its own props via LDS atomics, then stores
//      counts. No global atomics, no pre-zeroed global state -> the
//      separate memset dispatch of v4 is gone (workspace poison harmless:
//      counts/ovf_counts fully rewritten each launch).
//   2) per_prop_kernel: unchanged v4 body (W in 16 VGPRs, 4 waves split
//      each bucket, paired 2-entry reduction = 7 shfls/pair), except the
//      slots load is issued FIRST (it heads the slots->shfl->hs critical
//      path; the 16 W loads are independent and can stay in flight).
// Overflow (count > CAP=64; P ~ 0 for Poisson(6.55)) goes to deterministic
// per-bucket-block segments, swept by trailing gemv blocks.

#define H 512
#define D 2
#define CAP 64            // slots per property; Poisson(6.55) => P(>64) ~ 1e-30
#define KSPLIT 4          // waves per property
#define NB_BUCKET 128     // bucket blocks (each owns ceil(nprop/128) props)
#define MAX_PPB 320       // LDS counter capacity (supports nprop <= 40960)
#define OVFCAP 256        // per-bucket-block overflow segment capacity

// ---------------------------------------------------------------------------
// Shared per-bp GEMV body (verified layout), for overflow/fallback paths:
//   lane i, chunk k: W4[prop*256 + 64k + i] packs (W[h,0],W[h,1],W[h+1,0],W[h+1,1])
//                    hs2[bp*256  + 64k + i] packs (hs[h], hs[h+1]),  h = 128k + 2i
// ---------------------------------------------------------------------------
__device__ __forceinline__ void gemv_one_bp(
    const float* __restrict__ hs, const float* __restrict__ mask,
    const float* __restrict__ W,  const float* __restrict__ bias,
    float* __restrict__ out, int bp, int prop, int lane)
{
    const float2* h2 = (const float2*)(hs + (size_t)bp * H);
    const float4* w4 = (const float4*)(W + (size_t)prop * (H * D));

    float2 ha = h2[lane];
    float2 hb = h2[64 + lane];
    float2 hc = h2[128 + lane];
    float2 hd = h2[192 + lane];
    float4 wa = w4[lane];
    float4 wb = w4[64 + lane];
    float4 wc = w4[128 + lane];
    float4 wd = w4[192 + lane];

    float s0 = ha.x * wa.x + ha.y * wa.z
             + hb.x * wb.x + hb.y * wb.z
             + hc.x * wc.x + hc.y * wc.z
             + hd.x * wd.x + hd.y * wd.z;
    float s1 = ha.x * wa.y + ha.y * wa.w
             + hb.x * wb.y + hb.y * wb.w
             + hc.x * wc.y + hc.y * wc.w
             + hd.x * wd.y + hd.y * wd.w;

    #pragma unroll
    for (int off = 32; off > 0; off >>= 1) {
        s0 += __shfl_xor(s0, off, 64);
        s1 += __shfl_xor(s1, off, 64);
    }

    if (lane == 0) {
        const float m  = mask[bp];
        const float b0 = bias[(size_t)prop * D + 0];
        const float b1 = bias[(size_t)prop * D + 1];
        float2 r;
        r.x = (s0 + b0) * m;
        r.y = (s1 + b1) * m;
        *(float2*)(out + (size_t)bp * D) = r;
    }
}

// ---------------------------------------------------------------------------
// Kernel 1: fused zero+bucket. Block b owns props [p0, p1); scans ALL of
// props[] (256 KB; redundant across blocks but L2-served) and buckets only
// its own props with LDS atomics. Everything it writes is fully rewritten
// each launch -> no pre-zeroing dispatch needed.
// ---------------------------------------------------------------------------
__global__ __launch_bounds__(256) void bucket_zero_kernel(
    const int* __restrict__ props, int BP, int nprop,
    int* __restrict__ counts,       // [nprop] raw counts (may exceed CAP)
    int* __restrict__ slots,        // [nprop * CAP]
    int* __restrict__ ovf,          // [NB_BUCKET * OVFCAP]
    int* __restrict__ ovf_counts)   // [NB_BUCKET]
{
    __shared__ int lcnt[MAX_PPB];
    __shared__ int lovf;

    const int b   = blockIdx.x;
    const int ppb = (nprop + NB_BUCKET - 1) / NB_BUCKET;
    const int p0  = b * ppb;
    const int p1  = (p0 + ppb < nprop) ? (p0 + ppb) : nprop;
    const int np  = p1 - p0;
    if (np <= 0) { if (threadIdx.x == 0) ovf_counts[b] = 0; return; }

    for (int j = threadIdx.x; j < np; j += blockDim.x) lcnt[j] = 0;
    if (threadIdx.x == 0) lovf = 0;
    __syncthreads();

    const int4* props4 = (const int4*)props;
    const int n4 = BP >> 2;
    for (int i = threadIdx.x; i < n4; i += blockDim.x) {
        const int4 v = props4[i];
        const int base = i << 2;
        const int pv[4] = { v.x, v.y, v.z, v.w };
        #pragma unroll
        for (int c = 0; c < 4; ++c) {
            const int p = pv[c];
            if (p >= p0 && p < p1) {
                const int idx = atomicAdd(&lcnt[p - p0], 1);
                if (idx < CAP) {
                    slots[p * CAP + idx] = base + c;
                } else {
                    const int o = atomicAdd(&lovf, 1);
                    if (o < OVFCAP) ovf[b * OVFCAP + o] = base + c;
                }
            }
        }
    }
    // tail (BP not multiple of 4)
    for (int i = (n4 << 2) + threadIdx.x; i < BP; i += blockDim.x) {
        const int p = props[i];
        if (p >= p0 && p < p1) {
            const int idx = atomicAdd(&lcnt[p - p0], 1);
            if (idx < CAP) {
                slots[p * CAP + idx] = i;
            } else {
                const int o = atomicAdd(&lovf, 1);
                if (o < OVFCAP) ovf[b * OVFCAP + o] = i;
            }
        }
    }
    __syncthreads();

    for (int j = threadIdx.x; j < np; j += blockDim.x) counts[p0 + j] = lcnt[j];
    if (threadIdx.x == 0) ovf_counts[b] = (lovf < OVFCAP) ? lovf : OVFCAP;
}

// ---------------------------------------------------------------------------
// GEMV body for one prop's bucket slice owned by this wave (paired reduction).
// slots load issued FIRST: it heads the slots->shfl->hs critical path.
// ---------------------------------------------------------------------------
__device__ __forceinline__ void gemv_prop_wave(
    const float* __restrict__ hs, const float* __restrict__ mask,
    const float* __restrict__ W,  const float* __restrict__ bias,
    float* __restrict__ out, const int* __restrict__ slots,
    int p, int cnt, int k, int lane)
{
    const int nt = (cnt - k + KSPLIT - 1) / KSPLIT;   // my entry count (<=16)
    if (nt <= 0) return;

    // lane t holds the slot for my t-th entry (k + KSPLIT*t). Issued first.
    const int myslot = (lane < nt) ? slots[p * CAP + k + KSPLIT * lane] : 0;

    // W for this property, resident in 16 VGPRs (independent of slots load).
    const float4* w4 = (const float4*)(W + (size_t)p * (H * D));
    const float4 wa = w4[lane];
    const float4 wb = w4[64 + lane];
    const float4 wc = w4[128 + lane];
    const float4 wd = w4[192 + lane];
    const float2 bv = *(const float2*)(bias + (size_t)p * D);
    const float bsel = (lane & 1) ? bv.y : bv.x;

    for (int u = 0; u < nt; u += 2) {
        const int  bpA  = __shfl(myslot, u, 64);
        const bool hasB = (u + 1 < nt);
        const int  bpB  = __shfl(myslot, hasB ? (u + 1) : u, 64);

        const float2* hA = (const float2*)(hs + (size_t)bpA * H);
        float2 a0 = hA[lane];
        float2 a1 = hA[64 + lane];
        float2 a2 = hA[128 + lane];
        float2 a3 = hA[192 + lane];
        float2 c0, c1, c2, c3;
        if (hasB) {
            const float2* hB = (const float2*)(hs + (size_t)bpB * H);
            c0 = hB[lane];
            c1 = hB[64 + lane];
            c2 = hB[128 + lane];
            c3 = hB[192 + lane];
        } else {
            c0 = c1 = c2 = c3 = make_float2(0.f, 0.f);
        }

        float s0A = a0.x * wa.x + a0.y * wa.z
                  + a1.x * wb.x + a1.y * wb.z
                  + a2.x * wc.x + a2.y * wc.z
                  + a3.x * wd.x + a3.y * wd.z;
        float s1A = a0.x * wa.y + a0.y * wa.w
                  + a1.x * wb.y + a1.y * wb.w
                  + a2.x * wc.y + a2.y * wc.w
                  + a3.x * wd.y + a3.y * wd.w;
        float s0B = c0.x * wa.x + c0.y * wa.z
                  + c1.x * wb.x + c1.y * wb.z
                  + c2.x * wc.x + c2.y * wc.z
                  + c3.x * wd.x + c3.y * wd.z;
        float s1B = c0.x * wa.y + c0.y * wa.w
                  + c1.x * wb.y + c1.y * wb.w
                  + c2.x * wc.y + c2.y * wc.w
                  + c3.x * wd.y + c3.y * wd.w;

        // Joint reduction: 7 shfls for all four dot products.
        const bool o1 = (lane & 1) != 0;
        float keepA = o1 ? s1A : s0A;
        float sendA = o1 ? s0A : s1A;
        float vA = keepA + __shfl_xor(sendA, 1, 64);
        float keepB = o1 ? s1B : s0B;
        float sendB = o1 ? s0B : s1B;
        float vB = keepB + __shfl_xor(sendB, 1, 64);
        const bool o2 = (lane & 2) != 0;
        float keep = o2 ? vB : vA;
        float send = o2 ? vA : vB;
        float w = keep + __shfl_xor(send, 2, 64);
        #pragma unroll
        for (int off = 4; off <= 32; off <<= 1)
            w += __shfl_xor(w, off, 64);

        // lane 0: s0A, lane 1: s1A, lane 2: s0B, lane 3: s1B.
        if (lane < (hasB ? 4 : 2)) {
            const int bps = (lane & 2) ? bpB : bpA;
            const float m = mask[bps];
            out[(size_t)bps * D + (lane & 1)] = (w + bsel) * m;
        }
    }
}

// ---------------------------------------------------------------------------
// Kernel 2: blocks [0, nprop) -> per-prop GEMV (4-wave bucket split);
// blocks [nprop, nprop+NB_BUCKET) -> sweep overflow segment of bucket block
// (blockIdx - nprop) using the plain per-bp path (normally empty).
// ---------------------------------------------------------------------------
__global__ __launch_bounds__(256) void per_prop_kernel(
    const float* __restrict__ hs,
    const int*   __restrict__ props,
    const float* __restrict__ mask,
    const float* __restrict__ W,
    const float* __restrict__ bias,
    float*       __restrict__ out,
    const int*   __restrict__ counts,
    const int*   __restrict__ slots,
    const int*   __restrict__ ovf,
    const int*   __restrict__ ovf_counts,
    int nprop)
{
    const int k    = threadIdx.x >> 6;   // sub-wave 0..3
    const int lane = threadIdx.x & 63;

    if (blockIdx.x < (unsigned)nprop) {
        const int p = blockIdx.x;
        int cnt = counts[p];
        if (cnt > CAP) cnt = CAP;
        if (cnt == 0) return;
        gemv_prop_wave(hs, mask, W, bias, out, slots, p, cnt, k, lane);
    } else {
        const int b = blockIdx.x - nprop;      // bucket-block segment b
        const int n = ovf_counts[b];
        for (int i = k; i < n; i += KSPLIT) {
            const int bp = ovf[b * OVFCAP + i];
            gemv_one_bp(hs, mask, W, bias, out, bp, props[bp], lane);
        }
    }
}

// ---------------------------------------------------------------------------
// Fallback: original per-bp kernel (workspace too small / nprop too large).
// ---------------------------------------------------------------------------
__global__ __launch_bounds__(256) void adapter_gemv_kernel(
    const float* __restrict__ hs,
    const int*   __restrict__ props,
    const float* __restrict__ mask,
    const float* __restrict__ W,
    const float* __restrict__ bias,
    float* __restrict__ out,
    int BP)
{
    const int tid  = blockIdx.x * blockDim.x + threadIdx.x;
    const int bp   = tid >> 6;
    const int lane = tid & 63;
    if (bp >= BP) return;
    gemv_one_bp(hs, mask, W, bias, out, bp, props[bp], lane);
}

extern "C" void kernel_launch(void* const* d_in, const int* in_sizes, int n_in,
                              void* d_out, int out_size, void* d_ws, size_t ws_size,
                              hipStream_t stream) {
    const float* hs    = (const float*)d_in[0];
    const int*   props = (const int*)d_in[1];
    const float* mask  = (const float*)d_in[2];
    const float* W     = (const float*)d_in[3];
    const float* bias  = (const float*)d_in[4];
    float* out = (float*)d_out;

    const int BP    = in_sizes[1];                 // 512 * 128 = 65536 pairs
    const int nprop = in_sizes[3] / (H * D);       // 10000

    // Workspace layout (all int32):
    //   [0, nprop)                : counts (raw; may exceed CAP)
    //   slots at 256B-aligned off : nprop * CAP
    //   ovf   after slots         : NB_BUCKET * OVFCAP
    //   ovf_counts after ovf      : NB_BUCKET
    const size_t off_counts = 0;
    const size_t off_slots  = (((size_t)nprop * 4) + 255) & ~(size_t)255;
    const size_t off_ovf    = off_slots + (size_t)nprop * CAP * 4;
    const size_t off_ovfcnt = off_ovf + (size_t)NB_BUCKET * OVFCAP * 4;
    const size_t ws_needed  = off_ovfcnt + (size_t)NB_BUCKET * 4;

    const int ppb = (nprop + NB_BUCKET - 1) / NB_BUCKET;

    if (ws_size < ws_needed || ppb > MAX_PPB) {
        // Fallback: original verified per-bp path.
        const int threads = 256;
        const int blocks  = (BP * 64 + threads - 1) / threads;
        adapter_gemv_kernel<<<blocks, threads, 0, stream>>>(hs, props, mask, W, bias, out, BP);
        return;
    }

    int* counts     = (int*)((char*)d_ws + off_counts);
    int* slots      = (int*)((char*)d_ws + off_slots);
    int* ovf        = (int*)((char*)d_ws + off_ovf);
    int* ovf_counts = (int*)((char*)d_ws + off_ovfcnt);

    // Dispatch 1: fused zero+bucket (no global atomics, no pre-zeroing).
    bucket_zero_kernel<<<NB_BUCKET, 256, 0, stream>>>(
        props, BP, nprop, counts, slots, ovf, ovf_counts);

    // Dispatch 2: per-prop GEMV + overflow sweep.
    per_prop_kernel<<<nprop + NB_BUCKET, 256, 0, stream>>>(
        hs, props, mask, W, bias, out, counts, slots, ovf, ovf_counts, nprop);
}

// Round 6
// 45.231 us; speedup vs baseline: 5.9379x; 1.3086x over previous
//
#include <hip/hip_runtime.h>

// Batched gather-GEMV:
//   out[bp, d] = (sum_h hs[bp, h] * W[props[bp], h, d] + bias[props[bp], d]) * mask[bp]
// B*P = 65536, H = 512, D = 2, NPROP = 10000.
//
// v7: v4's verified 3-dispatch structure (memset + global-atomic bucket +
// per-prop GEMV) -- v6's ownership-scan bucket was latency-bound (128 blocks,
// 64 serial L2-latency iterations each ~= +16 us) and is reverted.
// Change vs v4: the GEMV uses 1536 persistent-style blocks (6/CU) that
// GRID-STRIDE over props, PREFETCHING the next prop's count + slot vector
// into registers while the current prop computes. This removes the
// per-block cold-start (10K blocks each living ~1 iteration in v4) and
// hides the slots->shfl->hs indirection latency. Overflow sweep is folded
// into the same kernel's tail.

#define H 512
#define D 2
#define CAP 48            // slots per property; Poisson(6.55) => P(>48) ~ 0
#define KSPLIT 4          // waves per property
#define SLOT_LANES 12     // lanes holding slot entries: k + 4*lane < CAP
#define GEMV_BLOCKS 1536  // 6 blocks/CU x 256 CUs
#define OVF_BLOCKS 64     // fallback-path cleanup blocks

// ---------------------------------------------------------------------------
// Shared per-bp GEMV body (verified layout), for overflow/fallback paths:
//   lane i, chunk k: W4[prop*256 + 64k + i] packs (W[h,0],W[h,1],W[h+1,0],W[h+1,1])
//                    hs2[bp*256  + 64k + i] packs (hs[h], hs[h+1]),  h = 128k + 2i
// ---------------------------------------------------------------------------
__device__ __forceinline__ void gemv_one_bp(
    const float* __restrict__ hs, const float* __restrict__ mask,
    const float* __restrict__ W,  const float* __restrict__ bias,
    float* __restrict__ out, int bp, int prop, int lane)
{
    const float2* h2 = (const float2*)(hs + (size_t)bp * H);
    const float4* w4 = (const float4*)(W + (size_t)prop * (H * D));

    float2 ha = h2[lane];
    float2 hb = h2[64 + lane];
    float2 hc = h2[128 + lane];
    float2 hd = h2[192 + lane];
    float4 wa = w4[lane];
    float4 wb = w4[64 + lane];
    float4 wc = w4[128 + lane];
    float4 wd = w4[192 + lane];

    float s0 = ha.x * wa.x + ha.y * wa.z
             + hb.x * wb.x + hb.y * wb.z
             + hc.x * wc.x + hc.y * wc.z
             + hd.x * wd.x + hd.y * wd.z;
    float s1 = ha.x * wa.y + ha.y * wa.w
             + hb.x * wb.y + hb.y * wb.w
             + hc.x * wc.y + hc.y * wc.w
             + hd.x * wd.y + hd.y * wd.w;

    #pragma unroll
    for (int off = 32; off > 0; off >>= 1) {
        s0 += __shfl_xor(s0, off, 64);
        s1 += __shfl_xor(s1, off, 64);
    }

    if (lane == 0) {
        const float m  = mask[bp];
        const float b0 = bias[(size_t)prop * D + 0];
        const float b1 = bias[(size_t)prop * D + 1];
        float2 r;
        r.x = (s0 + b0) * m;
        r.y = (s1 + b1) * m;
        *(float2*)(out + (size_t)bp * D) = r;
    }
}

// ---------------------------------------------------------------------------
// Kernel 1: bucket bp-pairs by property (global atomics; counts pre-zeroed
// by a 40 KB memset -- v4's verified structure).
// ---------------------------------------------------------------------------
__global__ __launch_bounds__(256) void bucket_kernel(
    const int* __restrict__ props, int BP,
    int* __restrict__ counts,   // [nprop], pre-zeroed
    int* __restrict__ slots,    // [nprop * CAP]
    int* __restrict__ ovf_cnt,  // [1], pre-zeroed
    int* __restrict__ ovf)      // [BP]
{
    int i = blockIdx.x * blockDim.x + threadIdx.x;
    const int stride = gridDim.x * blockDim.x;
    for (; i < BP; i += stride) {
        const int p = props[i];
        const int idx = atomicAdd(&counts[p], 1);
        if (idx < CAP) {
            slots[p * CAP + idx] = i;
        } else {
            const int o = atomicAdd(ovf_cnt, 1);
            ovf[o] = i;
        }
    }
}

// ---------------------------------------------------------------------------
// Per-prop GEMV body: cnt and this wave's slot vector already in registers.
// Paired 2-entry reduction (7 shfls / pair), W resident in 16 VGPRs.
// ---------------------------------------------------------------------------
__device__ __forceinline__ void gemv_prop_body(
    const float* __restrict__ hs, const float* __restrict__ mask,
    const float* __restrict__ W,  const float* __restrict__ bias,
    float* __restrict__ out, int p, int cnt, int myslot, int k, int lane)
{
    const int nt = (cnt - k + KSPLIT - 1) / KSPLIT;   // my entry count (<=12)
    if (nt <= 0) return;

    // W for this property, resident in 16 VGPRs.
    const float4* w4 = (const float4*)(W + (size_t)p * (H * D));
    const float4 wa = w4[lane];
    const float4 wb = w4[64 + lane];
    const float4 wc = w4[128 + lane];
    const float4 wd = w4[192 + lane];
    const float2 bv = *(const float2*)(bias + (size_t)p * D);
    const float bsel = (lane & 1) ? bv.y : bv.x;

    for (int u = 0; u < nt; u += 2) {
        const int  bpA  = __shfl(myslot, u, 64);
        const bool hasB = (u + 1 < nt);
        const int  bpB  = __shfl(myslot, hasB ? (u + 1) : u, 64);

        const float2* hA = (const float2*)(hs + (size_t)bpA * H);
        float2 a0 = hA[lane];
        float2 a1 = hA[64 + lane];
        float2 a2 = hA[128 + lane];
        float2 a3 = hA[192 + lane];
        float2 c0, c1, c2, c3;
        if (hasB) {
            const float2* hB = (const float2*)(hs + (size_t)bpB * H);
            c0 = hB[lane];
            c1 = hB[64 + lane];
            c2 = hB[128 + lane];
            c3 = hB[192 + lane];
        } else {
            c0 = c1 = c2 = c3 = make_float2(0.f, 0.f);
        }

        float s0A = a0.x * wa.x + a0.y * wa.z
                  + a1.x * wb.x + a1.y * wb.z
                  + a2.x * wc.x + a2.y * wc.z
                  + a3.x * wd.x + a3.y * wd.z;
        float s1A = a0.x * wa.y + a0.y * wa.w
                  + a1.x * wb.y + a1.y * wb.w
                  + a2.x * wc.y + a2.y * wc.w
                  + a3.x * wd.y + a3.y * wd.w;
        float s0B = c0.x * wa.x + c0.y * wa.z
                  + c1.x * wb.x + c1.y * wb.z
                  + c2.x * wc.x + c2.y * wc.z
                  + c3.x * wd.x + c3.y * wd.z;
        float s1B = c0.x * wa.y + c0.y * wa.w
                  + c1.x * wb.y + c1.y * wb.w
                  + c2.x * wc.y + c2.y * wc.w
                  + c3.x * wd.y + c3.y * wd.w;

        // Joint reduction: 7 shfls for all four dot products.
        const bool o1 = (lane & 1) != 0;
        float keepA = o1 ? s1A : s0A;
        float sendA = o1 ? s0A : s1A;
        float vA = keepA + __shfl_xor(sendA, 1, 64);
        float keepB = o1 ? s1B : s0B;
        float sendB = o1 ? s0B : s1B;
        float vB = keepB + __shfl_xor(sendB, 1, 64);
        const bool o2 = (lane & 2) != 0;
        float keep = o2 ? vB : vA;
        float send = o2 ? vA : vB;
        float w = keep + __shfl_xor(send, 2, 64);
        #pragma unroll
        for (int off = 4; off <= 32; off <<= 1)
            w += __shfl_xor(w, off, 64);

        // lane 0: s0A, lane 1: s1A, lane 2: s0B, lane 3: s1B.
        if (lane < (hasB ? 4 : 2)) {
            const int bps = (lane & 2) ? bpB : bpA;
            const float m = mask[bps];
            out[(size_t)bps * D + (lane & 1)] = (w + bsel) * m;
        }
    }
}

// ---------------------------------------------------------------------------
// Kernel 2: 1536 blocks grid-stride over props; next prop's (cnt, slots)
// prefetched into registers while the current prop computes. Tail: all
// blocks sweep the overflow list (normally empty: one scalar read of 0).
// ---------------------------------------------------------------------------
__global__ __launch_bounds__(256, 6) void per_prop_kernel(
    const float* __restrict__ hs,
    const int*   __restrict__ props,
    const float* __restrict__ mask,
    const float* __restrict__ W,
    const float* __restrict__ bias,
    float*       __restrict__ out,
    const int*   __restrict__ counts,
    const int*   __restrict__ slots,
    const int*   __restrict__ ovf_cnt,
    const int*   __restrict__ ovf,
    int nprop)
{
    const int k    = threadIdx.x >> 6;   // sub-wave 0..3
    const int lane = threadIdx.x & 63;
    const int G    = gridDim.x;

    // Prologue: load first prop's cnt + slot vector.
    int p = blockIdx.x;
    int cnt_cur  = 0;
    int slot_cur = 0;
    if (p < nprop) {
        cnt_cur = counts[p];
        if (lane < SLOT_LANES)
            slot_cur = slots[p * CAP + k + KSPLIT * lane];
    }

    for (; p < nprop; p += G) {
        // Prefetch next prop's cnt + slots (heads the indirection chain).
        const int pn = p + G;
        int cnt_next = 0, slot_next = 0;
        if (pn < nprop) {
            cnt_next = counts[pn];
            if (lane < SLOT_LANES)
                slot_next = slots[pn * CAP + k + KSPLIT * lane];
        }

        int cnt = (cnt_cur > CAP) ? CAP : cnt_cur;
        if (cnt > 0)
            gemv_prop_body(hs, mask, W, bias, out, p, cnt, slot_cur, k, lane);

        cnt_cur  = cnt_next;
        slot_cur = slot_next;
    }

    // Overflow sweep (normally empty).
    const int nov = *ovf_cnt;
    if (nov > 0) {
        const int gwid = blockIdx.x * KSPLIT + k;
        const int totw = G * KSPLIT;
        for (int i = gwid; i < nov; i += totw) {
            const int bp = ovf[i];
            gemv_one_bp(hs, mask, W, bias, out, bp, props[bp], lane);
        }
    }
}

// ---------------------------------------------------------------------------
// Fallback: original per-bp kernel (used only if workspace is too small).
// ---------------------------------------------------------------------------
__global__ __launch_bounds__(256) void adapter_gemv_kernel(
    const float* __restrict__ hs,
    const int*   __restrict__ props,
    const float* __restrict__ mask,
    const float* __restrict__ W,
    const float* __restrict__ bias,
    float* __restrict__ out,
    int BP)
{
    const int tid  = blockIdx.x * blockDim.x + threadIdx.x;
    const int bp   = tid >> 6;
    const int lane = tid & 63;
    if (bp >= BP) return;
    gemv_one_bp(hs, mask, W, bias, out, bp, props[bp], lane);
}

extern "C" void kernel_launch(void* const* d_in, const int* in_sizes, int n_in,
                              void* d_out, int out_size, void* d_ws, size_t ws_size,
                              hipStream_t stream) {
    const float* hs    = (const float*)d_in[0];
    const int*   props = (const int*)d_in[1];
    const float* mask  = (const float*)d_in[2];
    const float* W     = (const float*)d_in[3];
    const float* bias  = (const float*)d_in[4];
    float* out = (float*)d_out;

    const int BP    = in_sizes[1];                 // 512 * 128 = 65536 pairs
    const int nprop = in_sizes[3] / (H * D);       // 10000

    // Workspace layout (all int32):
    //   [0, nprop)                : counts
    //   [nprop]                   : ovf_cnt
    //   slots at 256B-aligned off : nprop * CAP
    //   ovf   after slots         : BP
    const size_t off_counts = 0;
    const size_t off_slots  = (((size_t)nprop * 4 + 4) + 255) & ~(size_t)255;
    const size_t off_ovf    = off_slots + (size_t)nprop * CAP * 4;
    const size_t ws_needed  = off_ovf + (size_t)BP * 4;

    if (ws_size < ws_needed) {
        // Not enough workspace: original verified path.
        const int threads = 256;
        const int blocks  = (BP * 64 + threads - 1) / threads;
        adapter_gemv_kernel<<<blocks, threads, 0, stream>>>(hs, props, mask, W, bias, out, BP);
        return;
    }

    int* counts  = (int*)((char*)d_ws + off_counts);
    int* ovf_cnt = counts + nprop;
    int* slots   = (int*)((char*)d_ws + off_slots);
    int* ovf     = (int*)((char*)d_ws + off_ovf);

    // Zero counts + ovf_cnt (graph-capture-safe stream op).
    hipMemsetAsync(counts, 0, off_slots, stream);

    {   // bucket
        const int threads = 256;
        int blocks = (BP + threads - 1) / threads;
        if (blocks > 1024) blocks = 1024;
        bucket_kernel<<<blocks, threads, 0, stream>>>(props, BP, counts, slots, ovf_cnt, ovf);
    }

    {   // per-prop gemv: persistent-style grid-stride blocks
        const int threads = 256;
        int blocks = GEMV_BLOCKS;
        if (blocks > nprop) blocks = nprop;
        per_prop_kernel<<<blocks, threads, 0, stream>>>(
            hs, props, mask, W, bias, out, counts, slots, ovf_cnt, ovf, nprop);
    }
}

// Round 7
// 43.274 us; speedup vs baseline: 6.2065x; 1.0452x over previous
//
#include <hip/hip_runtime.h>

// Batched gather-GEMV:
//   out[bp, d] = (sum_h hs[bp, h] * W[props[bp], h, d] + bias[props[bp], d]) * mask[bp]
// B*P = 65536, H = 512, D = 2, NPROP = 10000.
//
// v8: v4's verified 3-dispatch structure (memset + global-atomic bucket +
// one block per prop, 4-wave bucket split, W in 16 VGPRs, paired 2-entry
// reduction). v5 (grid.sync), v6 (ownership-scan bucket) and v7
// (persistent gemv) all regressed -> this structure is the right one.
// Micro-changes vs v4, each latency-mechanism-backed:
//   (1) slots load issued FIRST in the gemv body (heads the
//       slots->shfl->hs critical path; W loads are independent).
//   (2) mask[bp] loaded as soon as bp indices are known (was after the
//       reduction -> ~600 cy exposed on every pair-iteration tail).
//   (3) bucket scatter reads props as int4 (4x fewer loads, same atomics).

#define H 512
#define D 2
#define CAP 48            // slots per property; Poisson(6.55) => P(>48) ~ 0
#define KSPLIT 4          // waves per property
#define SLOT_LANES 12     // lanes holding slot entries: k + 4*lane < CAP
#define OVF_BLOCKS 64     // cleanup blocks for (theoretical) bucket overflow

// ---------------------------------------------------------------------------
// Shared per-bp GEMV body (verified layout), for overflow/fallback paths:
//   lane i, chunk k: W4[prop*256 + 64k + i] packs (W[h,0],W[h,1],W[h+1,0],W[h+1,1])
//                    hs2[bp*256  + 64k + i] packs (hs[h], hs[h+1]),  h = 128k + 2i
// ---------------------------------------------------------------------------
__device__ __forceinline__ void gemv_one_bp(
    const float* __restrict__ hs, const float* __restrict__ mask,
    const float* __restrict__ W,  const float* __restrict__ bias,
    float* __restrict__ out, int bp, int prop, int lane)
{
    const float2* h2 = (const float2*)(hs + (size_t)bp * H);
    const float4* w4 = (const float4*)(W + (size_t)prop * (H * D));

    float2 ha = h2[lane];
    float2 hb = h2[64 + lane];
    float2 hc = h2[128 + lane];
    float2 hd = h2[192 + lane];
    float4 wa = w4[lane];
    float4 wb = w4[64 + lane];
    float4 wc = w4[128 + lane];
    float4 wd = w4[192 + lane];

    float s0 = ha.x * wa.x + ha.y * wa.z
             + hb.x * wb.x + hb.y * wb.z
             + hc.x * wc.x + hc.y * wc.z
             + hd.x * wd.x + hd.y * wd.z;
    float s1 = ha.x * wa.y + ha.y * wa.w
             + hb.x * wb.y + hb.y * wb.w
             + hc.x * wc.y + hc.y * wc.w
             + hd.x * wd.y + hd.y * wd.w;

    #pragma unroll
    for (int off = 32; off > 0; off >>= 1) {
        s0 += __shfl_xor(s0, off, 64);
        s1 += __shfl_xor(s1, off, 64);
    }

    if (lane == 0) {
        const float m  = mask[bp];
        const float b0 = bias[(size_t)prop * D + 0];
        const float b1 = bias[(size_t)prop * D + 1];
        float2 r;
        r.x = (s0 + b0) * m;
        r.y = (s1 + b1) * m;
        *(float2*)(out + (size_t)bp * D) = r;
    }
}

// ---------------------------------------------------------------------------
// Kernel 1: bucket bp-pairs by property (global atomics; counts pre-zeroed
// by the 40 KB memset). int4-vectorized props read.
// ---------------------------------------------------------------------------
__global__ __launch_bounds__(256) void bucket_kernel(
    const int* __restrict__ props, int BP,
    int* __restrict__ counts,   // [nprop], pre-zeroed
    int* __restrict__ slots,    // [nprop * CAP]
    int* __restrict__ ovf_cnt,  // [1], pre-zeroed
    int* __restrict__ ovf)      // [BP]
{
    const int n4 = BP >> 2;
    const int4* props4 = (const int4*)props;
    int i = blockIdx.x * blockDim.x + threadIdx.x;
    const int stride = gridDim.x * blockDim.x;
    for (; i < n4; i += stride) {
        const int4 v = props4[i];
        const int base = i << 2;
        const int pv[4] = { v.x, v.y, v.z, v.w };
        #pragma unroll
        for (int c = 0; c < 4; ++c) {
            const int p = pv[c];
            const int idx = atomicAdd(&counts[p], 1);
            if (idx < CAP) {
                slots[p * CAP + idx] = base + c;
            } else {
                const int o = atomicAdd(ovf_cnt, 1);
                ovf[o] = base + c;
            }
        }
    }
    // tail (BP not a multiple of 4)
    for (i = (n4 << 2) + blockIdx.x * blockDim.x + threadIdx.x; i < BP; i += stride) {
        const int p = props[i];
        const int idx = atomicAdd(&counts[p], 1);
        if (idx < CAP) {
            slots[p * CAP + idx] = i;
        } else {
            const int o = atomicAdd(ovf_cnt, 1);
            ovf[o] = i;
        }
    }
}

// ---------------------------------------------------------------------------
// GEMV body for one prop's bucket slice owned by this wave (paired
// reduction). slots load issued FIRST; mask loaded as soon as bp known.
// ---------------------------------------------------------------------------
__device__ __forceinline__ void gemv_prop_wave(
    const float* __restrict__ hs, const float* __restrict__ mask,
    const float* __restrict__ W,  const float* __restrict__ bias,
    float* __restrict__ out, const int* __restrict__ slots,
    int p, int cnt, int k, int lane)
{
    const int nt = (cnt - k + KSPLIT - 1) / KSPLIT;   // my entry count (<=12)
    if (nt <= 0) return;

    // lane t holds the slot for my t-th entry (k + KSPLIT*t). Issued first:
    // it heads the slots->shfl->hs critical path.
    const int myslot = (lane < nt) ? slots[p * CAP + k + KSPLIT * lane] : 0;

    // W for this property, resident in 16 VGPRs (independent of slots load).
    const float4* w4 = (const float4*)(W + (size_t)p * (H * D));
    const float4 wa = w4[lane];
    const float4 wb = w4[64 + lane];
    const float4 wc = w4[128 + lane];
    const float4 wd = w4[192 + lane];
    const float2 bv = *(const float2*)(bias + (size_t)p * D);
    const float bsel = (lane & 1) ? bv.y : bv.x;

    for (int u = 0; u < nt; u += 2) {
        const int  bpA  = __shfl(myslot, u, 64);
        const bool hasB = (u + 1 < nt);
        const int  bpB  = __shfl(myslot, hasB ? (u + 1) : u, 64);

        // Early mask load (only the 4 result lanes need it); in flight
        // during the hs loads + FMAs + reduction.
        float mres = 0.f;
        if (lane < 4) mres = mask[(lane & 2) ? bpB : bpA];

        const float2* hA = (const float2*)(hs + (size_t)bpA * H);
        float2 a0 = hA[lane];
        float2 a1 = hA[64 + lane];
        float2 a2 = hA[128 + lane];
        float2 a3 = hA[192 + lane];
        float2 c0, c1, c2, c3;
        if (hasB) {
            const float2* hB = (const float2*)(hs + (size_t)bpB * H);
            c0 = hB[lane];
            c1 = hB[64 + lane];
            c2 = hB[128 + lane];
            c3 = hB[192 + lane];
        } else {
            c0 = c1 = c2 = c3 = make_float2(0.f, 0.f);
        }

        float s0A = a0.x * wa.x + a0.y * wa.z
                  + a1.x * wb.x + a1.y * wb.z
                  + a2.x * wc.x + a2.y * wc.z
                  + a3.x * wd.x + a3.y * wd.z;
        float s1A = a0.x * wa.y + a0.y * wa.w
                  + a1.x * wb.y + a1.y * wb.w
                  + a2.x * wc.y + a2.y * wc.w
                  + a3.x * wd.y + a3.y * wd.w;
        float s0B = c0.x * wa.x + c0.y * wa.z
                  + c1.x * wb.x + c1.y * wb.z
                  + c2.x * wc.x + c2.y * wc.z
                  + c3.x * wd.x + c3.y * wd.z;
        float s1B = c0.x * wa.y + c0.y * wa.w
                  + c1.x * wb.y + c1.y * wb.w
                  + c2.x * wc.y + c2.y * wc.w
                  + c3.x * wd.y + c3.y * wd.w;

        // Joint reduction: 7 shfls for all four dot products.
        const bool o1 = (lane & 1) != 0;
        float keepA = o1 ? s1A : s0A;
        float sendA = o1 ? s0A : s1A;
        float vA = keepA + __shfl_xor(sendA, 1, 64);
        float keepB = o1 ? s1B : s0B;
        float sendB = o1 ? s0B : s1B;
        float vB = keepB + __shfl_xor(sendB, 1, 64);
        const bool o2 = (lane & 2) != 0;
        float keep = o2 ? vB : vA;
        float send = o2 ? vA : vB;
        float w = keep + __shfl_xor(send, 2, 64);
        #pragma unroll
        for (int off = 4; off <= 32; off <<= 1)
            w += __shfl_xor(w, off, 64);

        // lane 0: s0A, lane 1: s1A, lane 2: s0B, lane 3: s1B.
        if (lane < (hasB ? 4 : 2)) {
            const int bps = (lane & 2) ? bpB : bpA;
            out[(size_t)bps * D + (lane & 1)] = (w + bsel) * mres;
        }
    }
}

// ---------------------------------------------------------------------------
// Kernel 2: blocks [0, nprop) -> per-prop GEMV (4-wave bucket split);
// blocks [nprop, nprop+OVF_BLOCKS) -> overflow sweep (normally empty).
// ---------------------------------------------------------------------------
__global__ __launch_bounds__(256) void per_prop_kernel(
    const float* __restrict__ hs,
    const int*   __restrict__ props,
    const float* __restrict__ mask,
    const float* __restrict__ W,
    const float* __restrict__ bias,
    float*       __restrict__ out,
    const int*   __restrict__ counts,
    const int*   __restrict__ slots,
    const int*   __restrict__ ovf_cnt,
    const int*   __restrict__ ovf,
    int nprop)
{
    const int k    = threadIdx.x >> 6;   // sub-wave 0..3
    const int lane = threadIdx.x & 63;

    if (blockIdx.x < (unsigned)nprop) {
        const int p = blockIdx.x;
        int cnt = counts[p];
        if (cnt > CAP) cnt = CAP;
        if (cnt == 0) return;
        gemv_prop_wave(hs, mask, W, bias, out, slots, p, cnt, k, lane);
    } else {
        const int wv = (blockIdx.x - nprop) * KSPLIT + k;
        const int n = *ovf_cnt;
        for (int i = wv; i < n; i += OVF_BLOCKS * KSPLIT) {
            const int bp = ovf[i];
            gemv_one_bp(hs, mask, W, bias, out, bp, props[bp], lane);
        }
    }
}

// ---------------------------------------------------------------------------
// Fallback: original per-bp kernel (used only if workspace is too small).
// ---------------------------------------------------------------------------
__global__ __launch_bounds__(256) void adapter_gemv_kernel(
    const float* __restrict__ hs,
    const int*   __restrict__ props,
    const float* __restrict__ mask,
    const float* __restrict__ W,
    const float* __restrict__ bias,
    float* __restrict__ out,
    int BP)
{
    const int tid  = blockIdx.x * blockDim.x + threadIdx.x;
    const int bp   = tid >> 6;
    const int lane = tid & 63;
    if (bp >= BP) return;
    gemv_one_bp(hs, mask, W, bias, out, bp, props[bp], lane);
}

extern "C" void kernel_launch(void* const* d_in, const int* in_sizes, int n_in,
                              void* d_out, int out_size, void* d_ws, size_t ws_size,
                              hipStream_t stream) {
    const float* hs    = (const float*)d_in[0];
    const int*   props = (const int*)d_in[1];
    const float* mask  = (const float*)d_in[2];
    const float* W     = (const float*)d_in[3];
    const float* bias  = (const float*)d_in[4];
    float* out = (float*)d_out;

    const int BP    = in_sizes[1];                 // 512 * 128 = 65536 pairs
    const int nprop = in_sizes[3] / (H * D);       // 10000

    // Workspace layout (all int32):
    //   [0, nprop)                : counts
    //   [nprop]                   : ovf_cnt
    //   slots at 256B-aligned off : nprop * CAP
    //   ovf   after slots         : BP
    const size_t off_counts = 0;
    const size_t off_slots  = (((size_t)nprop * 4 + 4) + 255) & ~(size_t)255;
    const size_t off_ovf    = off_slots + (size_t)nprop * CAP * 4;
    const size_t ws_needed  = off_ovf + (size_t)BP * 4;

    if (ws_size < ws_needed) {
        // Not enough workspace: original verified path.
        const int threads = 256;
        const int blocks  = (BP * 64 + threads - 1) / threads;
        adapter_gemv_kernel<<<blocks, threads, 0, stream>>>(hs, props, mask, W, bias, out, BP);
        return;
    }

    int* counts  = (int*)((char*)d_ws + off_counts);
    int* ovf_cnt = counts + nprop;
    int* slots   = (int*)((char*)d_ws + off_slots);
    int* ovf     = (int*)((char*)d_ws + off_ovf);

    // Zero counts + ovf_cnt (graph-capture-safe stream op).
    hipMemsetAsync(counts, 0, off_slots, stream);

    {   // bucket (int4-vectorized)
        const int threads = 256;
        int blocks = ((BP >> 2) + threads - 1) / threads;
        if (blocks > 1024) blocks = 1024;
        if (blocks < 1) blocks = 1;
        bucket_kernel<<<blocks, threads, 0, stream>>>(props, BP, counts, slots, ovf_cnt, ovf);
    }

    {   // per-prop gemv: one block per prop + overflow blocks
        const int threads = 256;
        const int blocks  = nprop + OVF_BLOCKS;
        per_prop_kernel<<<blocks, threads, 0, stream>>>(
            hs, props, mask, W, bias, out, counts, slots, ovf_cnt, ovf, nprop);
    }
}